// Round 10
// baseline (169.757 us; speedup 1.0000x reference)
//
#include <hip/hip_runtime.h>
#include <math.h>

#define B_DIM 128
#define N_DIM 512
#define D_DIM 512
#define H_DIM 256
#define K_SEL 8

typedef _Float16 half8 __attribute__((ext_vector_type(8)));
typedef float    f32x4 __attribute__((ext_vector_type(4)));

__device__ __forceinline__ void gload_lds16(const void* g, void* l) {
    __builtin_amdgcn_global_load_lds((const __attribute__((address_space(1))) void*)g,
                                     (__attribute__((address_space(3))) void*)l, 16, 0, 0);
}

// ---------------- Kernel 0: prep W1 -> transposed fp16 2-way split (l scaled by 2048) ----
// x = h + l'/2048 + eps, |eps| <= 2^-22|x|. Scaling keeps l' in fp16 normal range.
__global__ __launch_bounds__(256) void prep_w1_kernel(
    const float* __restrict__ W1,
    _Float16* __restrict__ w1t_h,
    _Float16* __restrict__ w1t_l)
{
    const int c = blockIdx.x;      // 256 cols
    const int t = threadIdx.x;     // 256 threads over k
    #pragma unroll
    for (int kk = 0; kk < D_DIM; kk += 256) {
        int k = kk + t;
        float x = W1[(size_t)k * H_DIM + c];
        _Float16 h = (_Float16)x;
        float r = x - (float)h;
        w1t_h[(size_t)c * D_DIM + k] = h;
        w1t_l[(size_t)c * D_DIM + k] = (_Float16)(r * 2048.0f);
    }
}

// ---------------- Kernel 1: fp16x2-split MFMA scorer, BM=256, 16 waves ----------------
// Grid: 256 WGs x 1024 threads (1 WG/CU; LDS 128 KB forces this). 16 waves 4Mx4N,
// per-wave 64x64 = 4x4 frags => acc = 64 VGPR.
// amdgpu_waves_per_eu(4,4): pin the VGPR cap at 512/4 = 128. __launch_bounds__'s
// second arg is only a MINIMUM occupancy hint — rounds 8/9 the compiler targeted
// 8 waves/EU (cap 64) and spilled the whole accumulator (WRITE_SIZE 170 MB),
// even though LDS already limits the kernel to 4 waves/EU.
__global__ __launch_bounds__(1024)
__attribute__((amdgpu_waves_per_eu(4, 4)))
void fused_scorer_mfma(
    const float* __restrict__ X,           // (65536, 512)
    const _Float16* __restrict__ w1t_h,    // (256, 512) [col][k]
    const _Float16* __restrict__ w1t_l,
    const float* __restrict__ b1,          // (256)
    const float* __restrict__ W2,          // (256)
    const float* __restrict__ b2p,         // scalar
    const float* __restrict__ base_logits, // (512)
    float* __restrict__ logits)            // (65536)
{
    // chunk16 = half8; chunk index = kc*256 + row/col (kc 0..3, 8 k each)
    __shared__ half8 Ah[2][1024], Al[2][1024];   // 64 KB
    __shared__ half8 Bh[2][1024], Bl[2][1024];   // 64 KB

    const int tid  = threadIdx.x;
    const int lane = tid & 63;
    const int wave = tid >> 6;            // 0..15
    const int wm   = (wave >> 2) << 6;    // 0,64,128,192
    const int wn   = (wave & 3) << 6;     // 0,64,128,192
    const int l15  = lane & 15;
    const int lg   = lane >> 4;           // 0..3
    const int row0 = blockIdx.x * 256;

    // staging maps: thread t -> row/col = t&255, k-chunk = t>>8 (chunk idx == tid)
    const int rc = tid & 255;
    const int kc = tid >> 8;              // 0..3
    const float*    xp  = X + (size_t)(row0 + rc) * D_DIM + kc * 8;
    const _Float16* bph = w1t_h + (size_t)rc * D_DIM + kc * 8;
    const _Float16* bpl = w1t_l + (size_t)rc * D_DIM + kc * 8;

    f32x4 acc[4][4];
    #pragma unroll
    for (int mi = 0; mi < 4; ++mi)
        #pragma unroll
        for (int nj = 0; nj < 4; ++nj)
            acc[mi][nj] = (f32x4){0.f, 0.f, 0.f, 0.f};

    // split 8 floats -> h/l' half8, write chunk tid (ds_write_b128, linear)
    auto split_write = [&](int buf, float4 va, float4 vb) {
        float e[8] = {va.x, va.y, va.z, va.w, vb.x, vb.y, vb.z, vb.w};
        half8 hh, ll;
        #pragma unroll
        for (int j = 0; j < 8; ++j) {
            _Float16 h = (_Float16)e[j];
            float r = e[j] - (float)h;
            hh[j] = h;
            ll[j] = (_Float16)(r * 2048.0f);
        }
        Ah[buf][tid] = hh;
        Al[buf][tid] = ll;
    };
    auto stage_b = [&](int buf, int kb) {
        gload_lds16(bph + kb, &Bh[buf][tid]);
        gload_lds16(bpl + kb, &Bl[buf][tid]);
    };

    // ---- prologue: stage k-step 0; prefetch A(1) ----
    float4 xa = *reinterpret_cast<const float4*>(xp);
    float4 xb = *reinterpret_cast<const float4*>(xp + 4);
    stage_b(0, 0);
    split_write(0, xa, xb);
    xa = *reinterpret_cast<const float4*>(xp + 32);
    xb = *reinterpret_cast<const float4*>(xp + 36);
    __syncthreads();

    for (int ks = 0; ks < 16; ++ks) {
        const int buf = ks & 1, nbuf = buf ^ 1;
        if (ks < 15) {                               // stage next k-step
            stage_b(nbuf, (ks + 1) * 32);            // DMA lands under MFMA block
            split_write(nbuf, xa, xb);
            if (ks < 14) {
                const int k2 = (ks + 2) * 32;
                xa = *reinterpret_cast<const float4*>(xp + k2);
                xb = *reinterpret_cast<const float4*>(xp + k2 + 4);
            }
        }
        #pragma unroll
        for (int nj = 0; nj < 4; ++nj) {
            int cb = lg * 256 + wn + nj * 16 + l15;
            half8 fbh = Bh[buf][cb];
            half8 fbl = Bl[buf][cb];
            #pragma unroll
            for (int mi = 0; mi < 4; ++mi) {
                int ca = lg * 256 + wm + mi * 16 + l15;
                half8 fah = Ah[buf][ca];
                half8 fal = Al[buf][ca];
                acc[mi][nj] = __builtin_amdgcn_mfma_f32_16x16x32_f16(fah, fbh, acc[mi][nj], 0, 0, 0);
                f32x4 t = __builtin_amdgcn_mfma_f32_16x16x32_f16(fah, fbl, (f32x4){0.f,0.f,0.f,0.f}, 0, 0, 0);
                t = __builtin_amdgcn_mfma_f32_16x16x32_f16(fal, fbh, t, 0, 0, 0);
                acc[mi][nj] += t * (1.0f / 2048.0f);
            }
        }
        __syncthreads();
    }

    // ---- epilogue: z = acc + b1 ; exact GELU ; dot W2 ; reduce 16 lanes + 4 N-waves ----
    float b1v[4], w2v[4];
    #pragma unroll
    for (int nj = 0; nj < 4; ++nj) {
        int col = wn + nj * 16 + l15;
        b1v[nj] = b1[col];
        w2v[nj] = W2[col];
    }
    float part[4][4];
    #pragma unroll
    for (int mi = 0; mi < 4; ++mi)
        #pragma unroll
        for (int r = 0; r < 4; ++r)
            part[mi][r] = 0.f;
    #pragma unroll
    for (int mi = 0; mi < 4; ++mi)
        #pragma unroll
        for (int nj = 0; nj < 4; ++nj)
            #pragma unroll
            for (int r = 0; r < 4; ++r) {
                float z = acc[mi][nj][r] + b1v[nj];
                float g = 0.5f * z * (1.0f + erff(z * 0.70710678118654752440f));
                part[mi][r] = fmaf(g, w2v[nj], part[mi][r]);
            }
    float* red = reinterpret_cast<float*>(&Ah[0][0]);  // dead A buffer; 4*256 floats
    #pragma unroll
    for (int mi = 0; mi < 4; ++mi)
        #pragma unroll
        for (int r = 0; r < 4; ++r) {
            float v = part[mi][r];
            v += __shfl_xor(v, 1, 16);
            v += __shfl_xor(v, 2, 16);
            v += __shfl_xor(v, 4, 16);
            v += __shfl_xor(v, 8, 16);
            if (l15 == 0)
                red[(wave & 3) * 256 + wm + mi * 16 + lg * 4 + r] = v;
        }
    __syncthreads();
    if (tid < 256) {
        float s = red[tid] + red[256 + tid] + red[512 + tid] + red[768 + tid];
        int grow = row0 + tid;
        logits[grow] = s + b2p[0] + base_logits[grow & (N_DIM - 1)];
    }
}

// ---------------- Kernel 2: softmax + top-8 + mask/importance/indices ----------------
__global__ __launch_bounds__(256) void softmax_topk_kernel(
    const float* __restrict__ logits,
    float* __restrict__ out_mask,
    float* __restrict__ out_importance,
    float* __restrict__ out_indices)
{
    const int b = blockIdx.x;
    const int tid = threadIdx.x;
    __shared__ float probs[N_DIM];
    __shared__ float redf[4];
    __shared__ int   redi[4];
    __shared__ int   sel_idx[K_SEL];

    float l0 = logits[b * N_DIM + tid];
    float l1 = logits[b * N_DIM + tid + 256];

    float m = fmaxf(l0, l1);
    #pragma unroll
    for (int s = 32; s >= 1; s >>= 1) m = fmaxf(m, __shfl_xor(m, s, 64));
    if ((tid & 63) == 0) redf[tid >> 6] = m;
    __syncthreads();
    float gm = fmaxf(fmaxf(redf[0], redf[1]), fmaxf(redf[2], redf[3]));
    __syncthreads();

    float e0 = expf(l0 - gm), e1 = expf(l1 - gm);
    float ssum = e0 + e1;
    #pragma unroll
    for (int s = 32; s >= 1; s >>= 1) ssum += __shfl_xor(ssum, s, 64);
    if ((tid & 63) == 0) redf[tid >> 6] = ssum;
    __syncthreads();
    float denom = redf[0] + redf[1] + redf[2] + redf[3];
    float p0 = e0 / denom, p1 = e1 / denom;
    probs[tid] = p0;
    probs[tid + 256] = p1;
    out_importance[b * N_DIM + tid] = p0;
    out_importance[b * N_DIM + tid + 256] = p1;
    __syncthreads();

    for (int it = 0; it < K_SEL; ++it) {
        float v0 = probs[tid]; int i0 = tid;
        float v1 = probs[tid + 256];
        if (v1 > v0) { v0 = v1; i0 = tid + 256; }
        #pragma unroll
        for (int s = 32; s >= 1; s >>= 1) {
            float ov = __shfl_xor(v0, s, 64);
            int   oi = __shfl_xor(i0, s, 64);
            if (ov > v0 || (ov == v0 && oi < i0)) { v0 = ov; i0 = oi; }
        }
        if ((tid & 63) == 0) { redf[tid >> 6] = v0; redi[tid >> 6] = i0; }
        __syncthreads();
        if (tid == 0) {
            float bv = redf[0]; int bi = redi[0];
            for (int w = 1; w < 4; ++w)
                if (redf[w] > bv || (redf[w] == bv && redi[w] < bi)) { bv = redf[w]; bi = redi[w]; }
            sel_idx[it] = bi;
            probs[bi] = -1.0f;
        }
        __syncthreads();
    }

    float mk0 = 0.f, mk1 = 0.f;
    #pragma unroll
    for (int i = 0; i < K_SEL; ++i) {
        if (sel_idx[i] == tid)       mk0 = 1.f;
        if (sel_idx[i] == tid + 256) mk1 = 1.f;
    }
    out_mask[b * N_DIM + tid] = mk0;
    out_mask[b * N_DIM + tid + 256] = mk1;

    if (tid < K_SEL) out_indices[b * K_SEL + tid] = (float)sel_idx[tid];
}

// ---------------- Kernel 3: gather selected rows (overwrites scratch last) ----------
__global__ __launch_bounds__(256) void gather_kernel(
    const float* __restrict__ X,
    const float* __restrict__ out_indices,
    float* __restrict__ out_selected)
{
    const int b = blockIdx.x;
    const int tid = threadIdx.x;
    __shared__ int sel[K_SEL];
    if (tid < K_SEL) sel[tid] = (int)out_indices[b * K_SEL + tid];
    __syncthreads();
    #pragma unroll
    for (int i = 0; i < 4; ++i) {
        int f = tid + 256 * i;
        int ki = f >> 7;
        int c4 = f & 127;
        float4 v = reinterpret_cast<const float4*>(
            X + ((size_t)b * N_DIM + sel[ki]) * D_DIM)[c4];
        reinterpret_cast<float4*>(
            out_selected + ((size_t)b * K_SEL + ki) * D_DIM)[c4] = v;
    }
}

extern "C" void kernel_launch(void* const* d_in, const int* in_sizes, int n_in,
                              void* d_out, int out_size, void* d_ws, size_t ws_size,
                              hipStream_t stream) {
    const float* X           = (const float*)d_in[0];
    const float* W1          = (const float*)d_in[1];
    const float* b1          = (const float*)d_in[2];
    const float* W2          = (const float*)d_in[3];
    const float* b2          = (const float*)d_in[4];
    const float* base_logits = (const float*)d_in[5];

    float* out            = (float*)d_out;
    float* out_selected   = out;                                  // 128*8*512 = 524288
    float* out_mask       = out_selected + B_DIM * K_SEL * D_DIM; // 128*512
    float* out_importance = out_mask + B_DIM * N_DIM;             // 128*512
    float* out_indices    = out_importance + B_DIM * N_DIM;       // 128*8

    // Scratch inside out_selected's region (gather overwrites it last):
    float*    logits = out_selected;                         // [0, 65536) f32
    _Float16* w1t_h  = (_Float16*)(out_selected + 65536);    // 131072 halfs
    _Float16* w1t_l  = (_Float16*)(out_selected + 131072);   // 131072 halfs

    hipLaunchKernelGGL(prep_w1_kernel, dim3(H_DIM), dim3(256), 0, stream,
                       W1, w1t_h, w1t_l);
    hipLaunchKernelGGL(fused_scorer_mfma, dim3((B_DIM * N_DIM) / 256), dim3(1024), 0, stream,
                       X, w1t_h, w1t_l, b1, W2, b2, base_logits, logits);
    hipLaunchKernelGGL(softmax_topk_kernel, dim3(B_DIM), dim3(256), 0, stream,
                       logits, out_mask, out_importance, out_indices);
    hipLaunchKernelGGL(gather_kernel, dim3(B_DIM), dim3(256), 0, stream,
                       X, out_indices, out_selected);
}

// Round 11
// 167.395 us; speedup vs baseline: 1.0141x; 1.0141x over previous
//
#include <hip/hip_runtime.h>
#include <math.h>

#define B_DIM 128
#define N_DIM 512
#define D_DIM 512
#define H_DIM 256
#define K_SEL 8

typedef _Float16 half8 __attribute__((ext_vector_type(8)));
typedef float    f32x4 __attribute__((ext_vector_type(4)));

__device__ __forceinline__ void gload_lds16(const void* g, void* l) {
    __builtin_amdgcn_global_load_lds((const __attribute__((address_space(1))) void*)g,
                                     (__attribute__((address_space(3))) void*)l, 16, 0, 0);
}

// ---------------- Kernel 0: prep W1 -> transposed fp16 2-way split (l scaled by 2048) ----
// x = h + l'/2048 + eps, |eps| <= 2^-22|x|. Scaling keeps l' in fp16 normal range.
__global__ __launch_bounds__(256) void prep_w1_kernel(
    const float* __restrict__ W1,
    _Float16* __restrict__ w1t_h,
    _Float16* __restrict__ w1t_l)
{
    const int c = blockIdx.x;      // 256 cols
    const int t = threadIdx.x;     // 256 threads over k
    #pragma unroll
    for (int kk = 0; kk < D_DIM; kk += 256) {
        int k = kk + t;
        float x = W1[(size_t)k * H_DIM + c];
        _Float16 h = (_Float16)x;
        float r = x - (float)h;
        w1t_h[(size_t)c * D_DIM + k] = h;
        w1t_l[(size_t)c * D_DIM + k] = (_Float16)(r * 2048.0f);
    }
}

// ---------------- Kernel 1: fp16x2-split MFMA scorer, BM=256, 16 waves ----------------
// Grid: 256 WGs x 1024 threads (1 WG/CU; LDS 128 KB forces this). 16 waves 4Mx4N,
// per-wave 64x64 = 4x4 frags => acc = 64 VGPR.
// __launch_bounds__(1024, 1): empirically this toolchain treats the 2nd arg with
// min-BLOCKS-per-CU-like semantics — (512,2)->cap128, (1024,default~2)->cap64,
// (1024,4)->cap64 [r8-r10: acc spilled, WRITE_SIZE 170 MB]. Request the MINIMUM
// occupancy (1 block = 16 waves = 4 waves/SIMD) so the cap relaxes to 128, which
// is also the hard launchability bound for a 16-wave workgroup.
__global__ __launch_bounds__(1024, 1)
void fused_scorer_mfma(
    const float* __restrict__ X,           // (65536, 512)
    const _Float16* __restrict__ w1t_h,    // (256, 512) [col][k]
    const _Float16* __restrict__ w1t_l,
    const float* __restrict__ b1,          // (256)
    const float* __restrict__ W2,          // (256)
    const float* __restrict__ b2p,         // scalar
    const float* __restrict__ base_logits, // (512)
    float* __restrict__ logits)            // (65536)
{
    // chunk16 = half8; chunk index = kc*256 + row/col (kc 0..3, 8 k each)
    __shared__ half8 Ah[2][1024], Al[2][1024];   // 64 KB
    __shared__ half8 Bh[2][1024], Bl[2][1024];   // 64 KB

    const int tid  = threadIdx.x;
    const int lane = tid & 63;
    const int wave = tid >> 6;            // 0..15
    const int wm   = (wave >> 2) << 6;    // 0,64,128,192
    const int wn   = (wave & 3) << 6;     // 0,64,128,192
    const int l15  = lane & 15;
    const int lg   = lane >> 4;           // 0..3
    const int row0 = blockIdx.x * 256;

    // staging maps: thread t -> row/col = t&255, k-chunk = t>>8 (chunk idx == tid)
    const int rc = tid & 255;
    const int kc = tid >> 8;              // 0..3
    const float*    xp  = X + (size_t)(row0 + rc) * D_DIM + kc * 8;
    const _Float16* bph = w1t_h + (size_t)rc * D_DIM + kc * 8;
    const _Float16* bpl = w1t_l + (size_t)rc * D_DIM + kc * 8;

    f32x4 acc[4][4];
    #pragma unroll
    for (int mi = 0; mi < 4; ++mi)
        #pragma unroll
        for (int nj = 0; nj < 4; ++nj)
            acc[mi][nj] = (f32x4){0.f, 0.f, 0.f, 0.f};

    // split 8 floats -> h/l' half8, write chunk tid (ds_write_b128, linear)
    auto split_write = [&](int buf, float4 va, float4 vb) {
        float e[8] = {va.x, va.y, va.z, va.w, vb.x, vb.y, vb.z, vb.w};
        half8 hh, ll;
        #pragma unroll
        for (int j = 0; j < 8; ++j) {
            _Float16 h = (_Float16)e[j];
            float r = e[j] - (float)h;
            hh[j] = h;
            ll[j] = (_Float16)(r * 2048.0f);
        }
        Ah[buf][tid] = hh;
        Al[buf][tid] = ll;
    };
    auto stage_b = [&](int buf, int kb) {
        gload_lds16(bph + kb, &Bh[buf][tid]);
        gload_lds16(bpl + kb, &Bl[buf][tid]);
    };

    // ---- prologue: stage k-step 0; prefetch A(1) ----
    float4 xa = *reinterpret_cast<const float4*>(xp);
    float4 xb = *reinterpret_cast<const float4*>(xp + 4);
    stage_b(0, 0);
    split_write(0, xa, xb);
    xa = *reinterpret_cast<const float4*>(xp + 32);
    xb = *reinterpret_cast<const float4*>(xp + 36);
    __syncthreads();

    for (int ks = 0; ks < 16; ++ks) {
        const int buf = ks & 1, nbuf = buf ^ 1;
        if (ks < 15) {                               // stage next k-step
            stage_b(nbuf, (ks + 1) * 32);            // DMA lands under MFMA block
            split_write(nbuf, xa, xb);
            if (ks < 14) {
                const int k2 = (ks + 2) * 32;
                xa = *reinterpret_cast<const float4*>(xp + k2);
                xb = *reinterpret_cast<const float4*>(xp + k2 + 4);
            }
        }
        #pragma unroll
        for (int nj = 0; nj < 4; ++nj) {
            int cb = lg * 256 + wn + nj * 16 + l15;
            half8 fbh = Bh[buf][cb];
            half8 fbl = Bl[buf][cb];
            #pragma unroll
            for (int mi = 0; mi < 4; ++mi) {
                int ca = lg * 256 + wm + mi * 16 + l15;
                half8 fah = Ah[buf][ca];
                half8 fal = Al[buf][ca];
                acc[mi][nj] = __builtin_amdgcn_mfma_f32_16x16x32_f16(fah, fbh, acc[mi][nj], 0, 0, 0);
                f32x4 t = __builtin_amdgcn_mfma_f32_16x16x32_f16(fah, fbl, (f32x4){0.f,0.f,0.f,0.f}, 0, 0, 0);
                t = __builtin_amdgcn_mfma_f32_16x16x32_f16(fal, fbh, t, 0, 0, 0);
                acc[mi][nj] += t * (1.0f / 2048.0f);
            }
        }
        __syncthreads();
    }

    // ---- epilogue: z = acc + b1 ; exact GELU ; dot W2 ; reduce 16 lanes + 4 N-waves ----
    float b1v[4], w2v[4];
    #pragma unroll
    for (int nj = 0; nj < 4; ++nj) {
        int col = wn + nj * 16 + l15;
        b1v[nj] = b1[col];
        w2v[nj] = W2[col];
    }
    float part[4][4];
    #pragma unroll
    for (int mi = 0; mi < 4; ++mi)
        #pragma unroll
        for (int r = 0; r < 4; ++r)
            part[mi][r] = 0.f;
    #pragma unroll
    for (int mi = 0; mi < 4; ++mi)
        #pragma unroll
        for (int nj = 0; nj < 4; ++nj)
            #pragma unroll
            for (int r = 0; r < 4; ++r) {
                float z = acc[mi][nj][r] + b1v[nj];
                float g = 0.5f * z * (1.0f + erff(z * 0.70710678118654752440f));
                part[mi][r] = fmaf(g, w2v[nj], part[mi][r]);
            }
    float* red = reinterpret_cast<float*>(&Ah[0][0]);  // dead A buffer; 4*256 floats
    #pragma unroll
    for (int mi = 0; mi < 4; ++mi)
        #pragma unroll
        for (int r = 0; r < 4; ++r) {
            float v = part[mi][r];
            v += __shfl_xor(v, 1, 16);
            v += __shfl_xor(v, 2, 16);
            v += __shfl_xor(v, 4, 16);
            v += __shfl_xor(v, 8, 16);
            if (l15 == 0)
                red[(wave & 3) * 256 + wm + mi * 16 + lg * 4 + r] = v;
        }
    __syncthreads();
    if (tid < 256) {
        float s = red[tid] + red[256 + tid] + red[512 + tid] + red[768 + tid];
        int grow = row0 + tid;
        logits[grow] = s + b2p[0] + base_logits[grow & (N_DIM - 1)];
    }
}

// ---------------- Kernel 2: softmax + top-8 + mask/importance/indices ----------------
__global__ __launch_bounds__(256) void softmax_topk_kernel(
    const float* __restrict__ logits,
    float* __restrict__ out_mask,
    float* __restrict__ out_importance,
    float* __restrict__ out_indices)
{
    const int b = blockIdx.x;
    const int tid = threadIdx.x;
    __shared__ float probs[N_DIM];
    __shared__ float redf[4];
    __shared__ int   redi[4];
    __shared__ int   sel_idx[K_SEL];

    float l0 = logits[b * N_DIM + tid];
    float l1 = logits[b * N_DIM + tid + 256];

    float m = fmaxf(l0, l1);
    #pragma unroll
    for (int s = 32; s >= 1; s >>= 1) m = fmaxf(m, __shfl_xor(m, s, 64));
    if ((tid & 63) == 0) redf[tid >> 6] = m;
    __syncthreads();
    float gm = fmaxf(fmaxf(redf[0], redf[1]), fmaxf(redf[2], redf[3]));
    __syncthreads();

    float e0 = expf(l0 - gm), e1 = expf(l1 - gm);
    float ssum = e0 + e1;
    #pragma unroll
    for (int s = 32; s >= 1; s >>= 1) ssum += __shfl_xor(ssum, s, 64);
    if ((tid & 63) == 0) redf[tid >> 6] = ssum;
    __syncthreads();
    float denom = redf[0] + redf[1] + redf[2] + redf[3];
    float p0 = e0 / denom, p1 = e1 / denom;
    probs[tid] = p0;
    probs[tid + 256] = p1;
    out_importance[b * N_DIM + tid] = p0;
    out_importance[b * N_DIM + tid + 256] = p1;
    __syncthreads();

    for (int it = 0; it < K_SEL; ++it) {
        float v0 = probs[tid]; int i0 = tid;
        float v1 = probs[tid + 256];
        if (v1 > v0) { v0 = v1; i0 = tid + 256; }
        #pragma unroll
        for (int s = 32; s >= 1; s >>= 1) {
            float ov = __shfl_xor(v0, s, 64);
            int   oi = __shfl_xor(i0, s, 64);
            if (ov > v0 || (ov == v0 && oi < i0)) { v0 = ov; i0 = oi; }
        }
        if ((tid & 63) == 0) { redf[tid >> 6] = v0; redi[tid >> 6] = i0; }
        __syncthreads();
        if (tid == 0) {
            float bv = redf[0]; int bi = redi[0];
            for (int w = 1; w < 4; ++w)
                if (redf[w] > bv || (redf[w] == bv && redi[w] < bi)) { bv = redf[w]; bi = redi[w]; }
            sel_idx[it] = bi;
            probs[bi] = -1.0f;
        }
        __syncthreads();
    }

    float mk0 = 0.f, mk1 = 0.f;
    #pragma unroll
    for (int i = 0; i < K_SEL; ++i) {
        if (sel_idx[i] == tid)       mk0 = 1.f;
        if (sel_idx[i] == tid + 256) mk1 = 1.f;
    }
    out_mask[b * N_DIM + tid] = mk0;
    out_mask[b * N_DIM + tid + 256] = mk1;

    if (tid < K_SEL) out_indices[b * K_SEL + tid] = (float)sel_idx[tid];
}

// ---------------- Kernel 3: gather selected rows (overwrites scratch last) ----------
__global__ __launch_bounds__(256) void gather_kernel(
    const float* __restrict__ X,
    const float* __restrict__ out_indices,
    float* __restrict__ out_selected)
{
    const int b = blockIdx.x;
    const int tid = threadIdx.x;
    __shared__ int sel[K_SEL];
    if (tid < K_SEL) sel[tid] = (int)out_indices[b * K_SEL + tid];
    __syncthreads();
    #pragma unroll
    for (int i = 0; i < 4; ++i) {
        int f = tid + 256 * i;
        int ki = f >> 7;
        int c4 = f & 127;
        float4 v = reinterpret_cast<const float4*>(
            X + ((size_t)b * N_DIM + sel[ki]) * D_DIM)[c4];
        reinterpret_cast<float4*>(
            out_selected + ((size_t)b * K_SEL + ki) * D_DIM)[c4] = v;
    }
}

extern "C" void kernel_launch(void* const* d_in, const int* in_sizes, int n_in,
                              void* d_out, int out_size, void* d_ws, size_t ws_size,
                              hipStream_t stream) {
    const float* X           = (const float*)d_in[0];
    const float* W1          = (const float*)d_in[1];
    const float* b1          = (const float*)d_in[2];
    const float* W2          = (const float*)d_in[3];
    const float* b2          = (const float*)d_in[4];
    const float* base_logits = (const float*)d_in[5];

    float* out            = (float*)d_out;
    float* out_selected   = out;                                  // 128*8*512 = 524288
    float* out_mask       = out_selected + B_DIM * K_SEL * D_DIM; // 128*512
    float* out_importance = out_mask + B_DIM * N_DIM;             // 128*512
    float* out_indices    = out_importance + B_DIM * N_DIM;       // 128*8

    // Scratch inside out_selected's region (gather overwrites it last):
    float*    logits = out_selected;                         // [0, 65536) f32
    _Float16* w1t_h  = (_Float16*)(out_selected + 65536);    // 131072 halfs
    _Float16* w1t_l  = (_Float16*)(out_selected + 131072);   // 131072 halfs

    hipLaunchKernelGGL(prep_w1_kernel, dim3(H_DIM), dim3(256), 0, stream,
                       W1, w1t_h, w1t_l);
    hipLaunchKernelGGL(fused_scorer_mfma, dim3((B_DIM * N_DIM) / 256), dim3(1024), 0, stream,
                       X, w1t_h, w1t_l, b1, W2, b2, base_logits, logits);
    hipLaunchKernelGGL(softmax_topk_kernel, dim3(B_DIM), dim3(256), 0, stream,
                       logits, out_mask, out_importance, out_indices);
    hipLaunchKernelGGL(gather_kernel, dim3(B_DIM), dim3(256), 0, stream,
                       X, out_indices, out_selected);
}

// Round 12
// 108.915 us; speedup vs baseline: 1.5586x; 1.5369x over previous
//
#include <hip/hip_runtime.h>
#include <math.h>

#define B_DIM 128
#define N_DIM 512
#define D_DIM 512
#define H_DIM 256
#define K_SEL 8

typedef _Float16 half8 __attribute__((ext_vector_type(8)));
typedef float    f32x4 __attribute__((ext_vector_type(4)));

__device__ __forceinline__ void gload_lds16(const void* g, void* l) {
    __builtin_amdgcn_global_load_lds((const __attribute__((address_space(1))) void*)g,
                                     (__attribute__((address_space(3))) void*)l, 16, 0, 0);
}

// ---------------- Kernel 0: prep W1 -> transposed fp16 2-way split (l scaled by 2048) ----
// x = h + l'/2048 + eps, |eps| <= 2^-22|x|. Scaling keeps l' in fp16 normal range.
__global__ __launch_bounds__(256) void prep_w1_kernel(
    const float* __restrict__ W1,
    _Float16* __restrict__ w1t_h,
    _Float16* __restrict__ w1t_l)
{
    const int c = blockIdx.x;      // 256 cols
    const int t = threadIdx.x;     // 256 threads over k
    #pragma unroll
    for (int kk = 0; kk < D_DIM; kk += 256) {
        int k = kk + t;
        float x = W1[(size_t)k * H_DIM + c];
        _Float16 h = (_Float16)x;
        float r = x - (float)h;
        w1t_h[(size_t)c * D_DIM + k] = h;
        w1t_l[(size_t)c * D_DIM + k] = (_Float16)(r * 2048.0f);
    }
}

// ---------------- Kernel 1: fp16x2-split MFMA scorer, BM=256 x BN=128, 512 thr -------
// Grid: 512 WGs = 256 row-tiles x 2 col-halves (colhalf = bid>>8: the pair sharing a
// row-tile lands on the SAME XCD -> A read once per L2). 8 waves 4Mx2N, per-wave
// 64x64 = 4x4 frags -> acc 64 VGPR; total live ~114 < the measured 128 cap of
// __launch_bounds__(512,2) [r7]. 1024-thread blocks are toolchain-capped at 64 VGPR
// (r8-r11: acc spilled, WRITE_SIZE 170 MB) — abandoned.
// Logit is separable across col-halves (GELU is per-hidden-col): each WG emits a
// partial logit array; kernel 2 sums lp0+lp1 deterministically.
__global__ __launch_bounds__(512, 2) void fused_scorer_mfma(
    const float* __restrict__ X,           // (65536, 512)
    const _Float16* __restrict__ w1t_h,    // (256, 512) [col][k]
    const _Float16* __restrict__ w1t_l,
    const float* __restrict__ b1,          // (256)
    const float* __restrict__ W2,          // (256)
    float* __restrict__ lp)                // (2, 65536) partial logits
{
    // chunk16 = half8. A chunk = kc*256 + row (kc 0..3, 8 k each); B chunk = kc*128 + col.
    __shared__ half8 Ah[2][1024], Al[2][1024];   // 64 KB
    __shared__ half8 Bh[2][512],  Bl[2][512];    // 32 KB

    const int tid  = threadIdx.x;
    const int lane = tid & 63;
    const int wave = tid >> 6;            // 0..7
    const int wm   = (wave >> 1) << 6;    // 0,64,128,192
    const int wn   = (wave & 1) << 6;     // 0,64  (local col within the 128-half)
    const int l15  = lane & 15;
    const int lg   = lane >> 4;           // 0..3
    const int rowtile = blockIdx.x & 255;
    const int colhalf = blockIdx.x >> 8;  // 0,1
    const int row0 = rowtile * 256;
    const int col0 = colhalf * 128;

    // A staging: thread t -> chunks t and t+512: rc = t&255, kc1 = t>>8 (0/1), kc2 = kc1+2
    const int rc  = tid & 255;
    const int kc1 = tid >> 8;
    const float* xp = X + (size_t)(row0 + rc) * D_DIM + kc1 * 8;
    // B staging: thread t -> chunk t: col = t&127, kcb = t>>7 (0..3); linear dest for DMA
    const _Float16* bph = w1t_h + (size_t)(col0 + (tid & 127)) * D_DIM + (tid >> 7) * 8;
    const _Float16* bpl = w1t_l + (size_t)(col0 + (tid & 127)) * D_DIM + (tid >> 7) * 8;

    f32x4 acc[4][4];
    #pragma unroll
    for (int mi = 0; mi < 4; ++mi)
        #pragma unroll
        for (int nj = 0; nj < 4; ++nj)
            acc[mi][nj] = (f32x4){0.f, 0.f, 0.f, 0.f};

    float4 xv[4];
    auto load_a = [&](int k0) {
        xv[0] = *reinterpret_cast<const float4*>(xp + k0);
        xv[1] = *reinterpret_cast<const float4*>(xp + k0 + 4);
        xv[2] = *reinterpret_cast<const float4*>(xp + k0 + 16);   // chunk kc1+2
        xv[3] = *reinterpret_cast<const float4*>(xp + k0 + 20);
    };
    auto split_write = [&](int buf) {
        #pragma unroll
        for (int q = 0; q < 2; ++q) {
            float e[8] = {xv[2*q].x, xv[2*q].y, xv[2*q].z, xv[2*q].w,
                          xv[2*q+1].x, xv[2*q+1].y, xv[2*q+1].z, xv[2*q+1].w};
            half8 hh, ll;
            #pragma unroll
            for (int j = 0; j < 8; ++j) {
                _Float16 h = (_Float16)e[j];
                float r = e[j] - (float)h;
                hh[j] = h;
                ll[j] = (_Float16)(r * 2048.0f);
            }
            Ah[buf][tid + q * 512] = hh;
            Al[buf][tid + q * 512] = ll;
        }
    };
    auto stage_b = [&](int buf, int kb) {
        gload_lds16(bph + kb, &Bh[buf][tid]);
        gload_lds16(bpl + kb, &Bl[buf][tid]);
    };

    // ---- prologue: stage k-step 0; prefetch A(1) ----
    load_a(0);
    stage_b(0, 0);
    split_write(0);
    load_a(32);
    __syncthreads();

    for (int ks = 0; ks < 16; ++ks) {
        const int buf = ks & 1, nbuf = buf ^ 1;
        if (ks < 15) {
            stage_b(nbuf, (ks + 1) * 32);            // DMA lands under MFMA block
            split_write(nbuf);
            if (ks < 14) load_a((ks + 2) * 32);
        }
        #pragma unroll
        for (int nj = 0; nj < 4; ++nj) {
            int cb = lg * 128 + wn + nj * 16 + l15;
            half8 fbh = Bh[buf][cb];
            half8 fbl = Bl[buf][cb];
            #pragma unroll
            for (int mi = 0; mi < 4; ++mi) {
                int ca = lg * 256 + wm + mi * 16 + l15;
                half8 fah = Ah[buf][ca];
                half8 fal = Al[buf][ca];
                acc[mi][nj] = __builtin_amdgcn_mfma_f32_16x16x32_f16(fah, fbh, acc[mi][nj], 0, 0, 0);
                f32x4 t = __builtin_amdgcn_mfma_f32_16x16x32_f16(fah, fbl, (f32x4){0.f,0.f,0.f,0.f}, 0, 0, 0);
                t = __builtin_amdgcn_mfma_f32_16x16x32_f16(fal, fbh, t, 0, 0, 0);
                acc[mi][nj] += t * (1.0f / 2048.0f);
            }
        }
        __syncthreads();
    }

    // ---- epilogue: z = acc + b1 ; exact GELU ; dot W2 ; reduce 16 lanes + 2 N-waves ----
    float b1v[4], w2v[4];
    #pragma unroll
    for (int nj = 0; nj < 4; ++nj) {
        int col = col0 + wn + nj * 16 + l15;
        b1v[nj] = b1[col];
        w2v[nj] = W2[col];
    }
    float part[4][4];
    #pragma unroll
    for (int mi = 0; mi < 4; ++mi)
        #pragma unroll
        for (int r = 0; r < 4; ++r)
            part[mi][r] = 0.f;
    #pragma unroll
    for (int mi = 0; mi < 4; ++mi)
        #pragma unroll
        for (int nj = 0; nj < 4; ++nj)
            #pragma unroll
            for (int r = 0; r < 4; ++r) {
                float z = acc[mi][nj][r] + b1v[nj];
                float g = 0.5f * z * (1.0f + erff(z * 0.70710678118654752440f));
                part[mi][r] = fmaf(g, w2v[nj], part[mi][r]);
            }
    float* red = reinterpret_cast<float*>(&Ah[0][0]);  // dead A buffer; 2*256 floats
    #pragma unroll
    for (int mi = 0; mi < 4; ++mi)
        #pragma unroll
        for (int r = 0; r < 4; ++r) {
            float v = part[mi][r];
            v += __shfl_xor(v, 1, 16);
            v += __shfl_xor(v, 2, 16);
            v += __shfl_xor(v, 4, 16);
            v += __shfl_xor(v, 8, 16);
            if (l15 == 0)
                red[(wave & 1) * 256 + wm + mi * 16 + lg * 4 + r] = v;
        }
    __syncthreads();
    if (tid < 256)
        lp[(size_t)colhalf * 65536 + row0 + tid] = red[tid] + red[256 + tid];
}

// ---------------- Kernel 2: softmax + top-8 + mask/importance/indices ----------------
__global__ __launch_bounds__(256) void softmax_topk_kernel(
    const float* __restrict__ lp,          // (2, 65536) partial logits
    const float* __restrict__ b2p,
    const float* __restrict__ base_logits,
    float* __restrict__ out_mask,
    float* __restrict__ out_importance,
    float* __restrict__ out_indices)
{
    const int b = blockIdx.x;
    const int tid = threadIdx.x;
    __shared__ float probs[N_DIM];
    __shared__ float redf[4];
    __shared__ int   redi[4];
    __shared__ int   sel_idx[K_SEL];

    const float b2v = b2p[0];
    int i0g = b * N_DIM + tid;
    int i1g = i0g + 256;
    float l0 = lp[i0g] + lp[65536 + i0g] + b2v + base_logits[tid];
    float l1 = lp[i1g] + lp[65536 + i1g] + b2v + base_logits[tid + 256];

    float m = fmaxf(l0, l1);
    #pragma unroll
    for (int s = 32; s >= 1; s >>= 1) m = fmaxf(m, __shfl_xor(m, s, 64));
    if ((tid & 63) == 0) redf[tid >> 6] = m;
    __syncthreads();
    float gm = fmaxf(fmaxf(redf[0], redf[1]), fmaxf(redf[2], redf[3]));
    __syncthreads();

    float e0 = expf(l0 - gm), e1 = expf(l1 - gm);
    float ssum = e0 + e1;
    #pragma unroll
    for (int s = 32; s >= 1; s >>= 1) ssum += __shfl_xor(ssum, s, 64);
    if ((tid & 63) == 0) redf[tid >> 6] = ssum;
    __syncthreads();
    float denom = redf[0] + redf[1] + redf[2] + redf[3];
    float p0 = e0 / denom, p1 = e1 / denom;
    probs[tid] = p0;
    probs[tid + 256] = p1;
    out_importance[b * N_DIM + tid] = p0;
    out_importance[b * N_DIM + tid + 256] = p1;
    __syncthreads();

    for (int it = 0; it < K_SEL; ++it) {
        float v0 = probs[tid]; int i0 = tid;
        float v1 = probs[tid + 256];
        if (v1 > v0) { v0 = v1; i0 = tid + 256; }
        #pragma unroll
        for (int s = 32; s >= 1; s >>= 1) {
            float ov = __shfl_xor(v0, s, 64);
            int   oi = __shfl_xor(i0, s, 64);
            if (ov > v0 || (ov == v0 && oi < i0)) { v0 = ov; i0 = oi; }
        }
        if ((tid & 63) == 0) { redf[tid >> 6] = v0; redi[tid >> 6] = i0; }
        __syncthreads();
        if (tid == 0) {
            float bv = redf[0]; int bi = redi[0];
            for (int w = 1; w < 4; ++w)
                if (redf[w] > bv || (redf[w] == bv && redi[w] < bi)) { bv = redf[w]; bi = redi[w]; }
            sel_idx[it] = bi;
            probs[bi] = -1.0f;
        }
        __syncthreads();
    }

    float mk0 = 0.f, mk1 = 0.f;
    #pragma unroll
    for (int i = 0; i < K_SEL; ++i) {
        if (sel_idx[i] == tid)       mk0 = 1.f;
        if (sel_idx[i] == tid + 256) mk1 = 1.f;
    }
    out_mask[b * N_DIM + tid] = mk0;
    out_mask[b * N_DIM + tid + 256] = mk1;

    if (tid < K_SEL) out_indices[b * K_SEL + tid] = (float)sel_idx[tid];
}

// ---------------- Kernel 3: gather selected rows (overwrites scratch last) ----------
__global__ __launch_bounds__(256) void gather_kernel(
    const float* __restrict__ X,
    const float* __restrict__ out_indices,
    float* __restrict__ out_selected)
{
    const int b = blockIdx.x;
    const int tid = threadIdx.x;
    __shared__ int sel[K_SEL];
    if (tid < K_SEL) sel[tid] = (int)out_indices[b * K_SEL + tid];
    __syncthreads();
    #pragma unroll
    for (int i = 0; i < 4; ++i) {
        int f = tid + 256 * i;
        int ki = f >> 7;
        int c4 = f & 127;
        float4 v = reinterpret_cast<const float4*>(
            X + ((size_t)b * N_DIM + sel[ki]) * D_DIM)[c4];
        reinterpret_cast<float4*>(
            out_selected + ((size_t)b * K_SEL + ki) * D_DIM)[c4] = v;
    }
}

extern "C" void kernel_launch(void* const* d_in, const int* in_sizes, int n_in,
                              void* d_out, int out_size, void* d_ws, size_t ws_size,
                              hipStream_t stream) {
    const float* X           = (const float*)d_in[0];
    const float* W1          = (const float*)d_in[1];
    const float* b1          = (const float*)d_in[2];
    const float* W2          = (const float*)d_in[3];
    const float* b2          = (const float*)d_in[4];
    const float* base_logits = (const float*)d_in[5];

    float* out            = (float*)d_out;
    float* out_selected   = out;                                  // 128*8*512 = 524288
    float* out_mask       = out_selected + B_DIM * K_SEL * D_DIM; // 128*512
    float* out_importance = out_mask + B_DIM * N_DIM;             // 128*512
    float* out_indices    = out_importance + B_DIM * N_DIM;       // 128*8

    // Scratch inside out_selected's region (gather overwrites it last):
    //   [0      .. 131072) lp: 2 x 65536 partial logits (f32)
    //   [131072 .. 196608) w1t_h (131072 halfs)
    //   [196608 .. 262144) w1t_l (131072 halfs)
    float*    lp     = out_selected;
    _Float16* w1t_h  = (_Float16*)(out_selected + 131072);
    _Float16* w1t_l  = (_Float16*)(out_selected + 196608);

    hipLaunchKernelGGL(prep_w1_kernel, dim3(H_DIM), dim3(256), 0, stream,
                       W1, w1t_h, w1t_l);
    hipLaunchKernelGGL(fused_scorer_mfma, dim3(512), dim3(512), 0, stream,
                       X, w1t_h, w1t_l, b1, W2, lp);
    hipLaunchKernelGGL(softmax_topk_kernel, dim3(B_DIM), dim3(256), 0, stream,
                       lp, b2, base_logits, out_mask, out_importance, out_indices);
    hipLaunchKernelGGL(gather_kernel, dim3(B_DIM), dim3(256), 0, stream,
                       X, out_indices, out_selected);
}